// Round 3
// baseline (454.200 us; speedup 1.0000x reference)
//
#include <hip/hip_runtime.h>
#include <hip/hip_bf16.h>

typedef unsigned short u16;
typedef unsigned long long u64;
typedef u16 us8 __attribute__((ext_vector_type(8)));
typedef __bf16 bf8_t __attribute__((ext_vector_type(8)));
typedef float f32x4 __attribute__((ext_vector_type(4)));

__device__ __forceinline__ float b2f(u16 u) {
    return __uint_as_float(((unsigned int)u) << 16);
}
__device__ __forceinline__ u16 f2b(float f) {
    union { __hip_bfloat16 h; u16 u; } v;
    v.h = __float2bfloat16(f);
    return v.u;
}
__device__ __forceinline__ f32x4 mfma16(bf8_t a, bf8_t b, f32x4 c) {
    return __builtin_amdgcn_mfma_f32_16x16x32_bf16(a, b, c, 0, 0, 0);
}
__device__ __forceinline__ void gload_lds16(const u16* g, u16* lds_base) {
    __builtin_amdgcn_global_load_lds((const __attribute__((address_space(1))) unsigned int*)g,
                                     (__attribute__((address_space(3))) unsigned int*)lds_base,
                                     16, 0, 0);
}

// ---------------- fp32 -> bf16 convert (8 elems/thread)
__global__ __launch_bounds__(256) void f32_to_bf16(const float* __restrict__ src,
                                                   u16* __restrict__ dst, int n8) {
    int idx = blockIdx.x * 256 + threadIdx.x;
    if (idx >= n8) return;
    float4 f0 = ((const float4*)src)[idx * 2];
    float4 f1 = ((const float4*)src)[idx * 2 + 1];
    us8 o;
    o[0] = f2b(f0.x); o[1] = f2b(f0.y); o[2] = f2b(f0.z); o[3] = f2b(f0.w);
    o[4] = f2b(f1.x); o[5] = f2b(f1.y); o[6] = f2b(f1.z); o[7] = f2b(f1.w);
    ((us8*)dst)[idx] = o;
}

// ---------------- m201-faithful 256x256 8-phase GEMM: C[m,n] = sum_k A[m,k]*B[n,k].
// BM=BN=256 BK=64, K=2048 fixed (32 k-tiles). 512 threads = 8 waves (2M x 4N),
// per-wave 128x64 out (8 m-frags x 4 n-frags). LDS 128KB (2 bufs x (A 32KB + B 32KB)).
// Per K-tile 4 phases: {quadrant ds_reads (swizzled) | 1 half-tile stage | bar |
// lgkm0 | 16 MFMA @setprio | bar}. Stage: ph1/2 B(t+1)->other buf, ph3/4 A(t+2)->own buf.
// vmcnt(4) once per tile: last 2 staged halves stay in flight across the boundary.
#define BARX() __builtin_amdgcn_s_barrier()
#define LGKM0() do { asm volatile("s_waitcnt lgkmcnt(0)" ::: "memory"); \
                     __builtin_amdgcn_sched_barrier(0); } while (0)
#define VM4()   do { asm volatile("s_waitcnt vmcnt(4)" ::: "memory"); \
                     __builtin_amdgcn_sched_barrier(0); } while (0)

template<int SF32>
__global__ __launch_bounds__(512, 2) void gemm256(const u16* __restrict__ A,
                                                  const u16* __restrict__ B,
                                                  void* __restrict__ Cout, int ldc) {
    __shared__ u16 LA[2][256 * 64];   // [buf][row*64 + k] (st_16x32-swizzled contents)
    __shared__ u16 LB[2][256 * 64];

    const int tid = threadIdx.x;
    const int w = tid >> 6, lane = tid & 63;
    const int lm = lane & 15, lq = lane >> 4;
    const int wm = w >> 2, wn = w & 3;     // 2M x 4N wave grid, wave owns 128x64

    // XCD-aware bijective swizzle (grid % 8 == 0); 16 consecutive wg share an nt.
    const int bid = blockIdx.x;
    const int nper = gridDim.x >> 3;
    const int wg = (bid & 7) * nper + (bid >> 3);
    const int mt = wg & 15, nt = wg >> 4;
    const int m0 = mt * 256, n0 = nt * 256;

    // Pre-swizzled global source so linear global_load_lds lands st_16x32-swizzled
    // (bit5 ^= bit9 involution; lane bit1 <-> lane bit5). Rule #21: both-sides.
    const int lp = lane ^ ((lane & 32) >> 4);
    const int srow = lp >> 3;              // 0..7
    const int scol = (lp & 7) * 8;         // u16 col 0..56

    const u16* Ag = A + (size_t)(m0 + srow) * 2048 + scol;
    const u16* Bg = B + (size_t)(n0 + srow) * 2048 + scol;

    // half-tile stage: 128 rows x 64 k (16KB) = 8 waves x 2 instr x 1KB slices
#define STAGE_A(c, h, kt) do { \
    _Pragma("unroll") \
    for (int i = 0; i < 2; i++) { \
        int R = w * 2 + i; \
        gload_lds16(Ag + (size_t)((h) * 128 + R * 8) * 2048 + (kt) * 64, \
                    &LA[c][((h) * 128 + R * 8) * 64]); \
    } } while (0)

#define STAGE_B(c, h, kt) do { \
    _Pragma("unroll") \
    for (int i = 0; i < 2; i++) { \
        int R = w * 2 + i; \
        gload_lds16(Bg + (size_t)((h) * 128 + R * 8) * 2048 + (kt) * 64, \
                    &LB[c][((h) * 128 + R * 8) * 64]); \
    } } while (0)

    bf8_t af[8][2], bfr[4][2];
    f32x4 acc[8][4] = {};

#define RD_A(c, mh) do { \
    _Pragma("unroll") \
    for (int m = 0; m < 4; m++) \
    _Pragma("unroll") \
    for (int ks = 0; ks < 2; ks++) { \
        int o = (wm * 128 + ((mh) * 4 + m) * 16 + lm) * 128 + ks * 64 + lq * 16; \
        o ^= ((o >> 9) & 1) << 5; \
        af[(mh) * 4 + m][ks] = *(const bf8_t*)((const char*)&LA[c][0] + o); \
    } } while (0)

#define RD_B(c, nh) do { \
    _Pragma("unroll") \
    for (int n = 0; n < 2; n++) \
    _Pragma("unroll") \
    for (int ks = 0; ks < 2; ks++) { \
        int o = (wn * 64 + ((nh) * 2 + n) * 16 + lm) * 128 + ks * 64 + lq * 16; \
        o ^= ((o >> 9) & 1) << 5; \
        bfr[(nh) * 2 + n][ks] = *(const bf8_t*)((const char*)&LB[c][0] + o); \
    } } while (0)

#define QUAD(mh, nh) do { \
    __builtin_amdgcn_s_setprio(1); \
    _Pragma("unroll") \
    for (int m = 0; m < 4; m++) \
    _Pragma("unroll") \
    for (int n = 0; n < 2; n++) \
    _Pragma("unroll") \
    for (int ks = 0; ks < 2; ks++) \
        acc[(mh) * 4 + m][(nh) * 2 + n] = mfma16(af[(mh) * 4 + m][ks], \
            bfr[(nh) * 2 + n][ks], acc[(mh) * 4 + m][(nh) * 2 + n]); \
    __builtin_amdgcn_s_setprio(0); \
    } while (0)

    // phases: ph1 Q(0,0)[ds A0-3,B0-1]; ph2 Q(1,0)[ds A4-7]; ph3 Q(0,1)[ds B2-3];
    // ph4 Q(1,1)[no ds]. A consumed end-ph2, B consumed end-ph3 (all waves, via bars).
#define TILE(c, tB, tA) do { \
    RD_A(c, 0); RD_B(c, 0); \
    STAGE_B((c) ^ 1, 0, tB); \
    BARX(); LGKM0(); \
    QUAD(0, 0); \
    BARX(); \
    RD_A(c, 1); \
    STAGE_B((c) ^ 1, 1, tB); \
    BARX(); LGKM0(); \
    QUAD(1, 0); \
    BARX(); \
    RD_B(c, 1); \
    STAGE_A(c, 0, tA); \
    BARX(); LGKM0(); \
    QUAD(0, 1); \
    BARX(); \
    STAGE_A(c, 1, tA); \
    QUAD(1, 1); \
    VM4(); \
    BARX(); \
} while (0)

    // prologue: tile0 A+B -> buf0, tile1 A -> buf1 (B(1) staged during tile0).
    // VM4 leaves A(1) halves in flight; tile0 fully landed.
    STAGE_A(0, 0, 0); STAGE_A(0, 1, 0);
    STAGE_B(0, 0, 0); STAGE_B(0, 1, 0);
    STAGE_A(1, 0, 1); STAGE_A(1, 1, 1);
    VM4();
    BARX();

    for (int it = 0; it < 16; it++) {
        const int t0 = 2 * it, t1 = 2 * it + 1;
        const int tB0 = t1;                              // B(t0+1)
        const int tA0 = (t0 + 2 < 32) ? t0 + 2 : 31;     // A(t0+2), clamped dummy at tail
        const int tB1 = (t1 + 1 < 32) ? t1 + 1 : 31;
        const int tA1 = (t1 + 2 < 32) ? t1 + 2 : 31;
        TILE(0, tB0, tA0);
        TILE(1, tB1, tA1);
    }

    // epilogue
#pragma unroll
    for (int m = 0; m < 8; m++)
#pragma unroll
        for (int n = 0; n < 4; n++)
#pragma unroll
            for (int r = 0; r < 4; r++) {
                int row = m0 + wm * 128 + m * 16 + lq * 4 + r;
                int col = n0 + wn * 64 + n * 16 + lm;
                if (SF32)
                    ((float*)Cout)[(size_t)row * ldc + col] = acc[m][n][r];
                else
                    ((u16*)Cout)[(size_t)row * ldc + col] = f2b(acc[m][n][r]);
            }
#undef TILE
#undef QUAD
#undef RD_A
#undef RD_B
#undef STAGE_A
#undef STAGE_B
}

// ---------------- Fused: RoPE in-place on Q,K  +  V transpose -> VT (B,H,D,S)
__global__ __launch_bounds__(256) void rope_vt(u16* __restrict__ qkv, u16* __restrict__ VT) {
    __shared__ u16 T[64 * 136];
    const int tid = threadIdx.x;
    const int s0 = blockIdx.x * 64;
    const int bh = blockIdx.y;
    const int b = bh >> 4, h = bh & 15;
#pragma unroll
    for (int p = 0; p < 4; p++) {
        int sl = p * 16 + (tid >> 4);
        int d0 = (tid & 15) * 8;
        *(us8*)&T[sl * 136 + d0] =
            *(const us8*)(qkv + ((size_t)(b * 2048 + s0 + sl)) * 6144 + 4096 + h * 128 + d0);
    }
#pragma unroll
    for (int p = 0; p < 2; p++) {
        int task = p * 256 + tid;
        int sl = task >> 3;
        int jg = task & 7;
        size_t base = ((size_t)(b * 2048 + s0 + sl)) * 6144 + h * 128 + jg * 8;
        us8 qlo = *(const us8*)(qkv + base);
        us8 qhi = *(const us8*)(qkv + base + 64);
        us8 klo = *(const us8*)(qkv + base + 2048);
        us8 khi = *(const us8*)(qkv + base + 2048 + 64);
        us8 oql, oqh, okl, okh;
        float s = (float)(s0 + sl);
#pragma unroll
        for (int e = 0; e < 8; e++) {
            int j = jg * 8 + e;
            float inv = __expf((float)j * (-9.210340371976184f / 64.f));
            float ang = s * inv;
            float sn, c;
            __sincosf(ang, &sn, &c);
            float q1 = b2f(qlo[e]), q2 = b2f(qhi[e]);
            oql[e] = f2b(q1 * c - q2 * sn);
            oqh[e] = f2b(q2 * c + q1 * sn);
            float k1 = b2f(klo[e]), k2 = b2f(khi[e]);
            okl[e] = f2b(k1 * c - k2 * sn);
            okh[e] = f2b(k2 * c + k1 * sn);
        }
        *(us8*)(qkv + base) = oql;
        *(us8*)(qkv + base + 64) = oqh;
        *(us8*)(qkv + base + 2048) = okl;
        *(us8*)(qkv + base + 2048 + 64) = okh;
    }
    __syncthreads();
#pragma unroll
    for (int p = 0; p < 4; p++) {
        int idx = p * 256 + tid;
        int d = idx & 127;
        int sg = idx >> 7;
        us8 v;
#pragma unroll
        for (int i = 0; i < 8; i++) v[i] = T[(sg * 8 + i) * 136 + d];
        *(us8*)&VT[((size_t)bh * 128 + d) * 2048 + s0 + sg * 8] = v;
    }
}

// ---------------- Flash attention v5: balanced causal pairing (33 qg-tile units/block).
#define ATT_SCALE 0.08838834764831845f

__global__ __launch_bounds__(256, 2) void attn_flash(const u16* __restrict__ qkv, const u16* __restrict__ VT,
                                                     u16* __restrict__ AO) {
    const int bid = blockIdx.x;
    const int swz = (bid & 7) * 64 + (bid >> 3);
    const int bh = swz >> 4;          // 0..31
    const int pair = swz & 15;        // 0..15
    const int b = bh >> 4, h = bh & 15;
    const int tid = threadIdx.x, lane = tid & 63, wave = tid >> 6;
    const int lm = lane & 15, lq = lane >> 4;

    const int jq0 = 31 - pair;        // high q-subtile (64-row units), always active
    const int jq1 = pair;             // low q-subtile, active for kt <= jq1
    const int ktmax = jq0;

    __shared__ u16 Kt[64 * 136];      // [kpos][d]
    __shared__ u16 Vt[128 * 72];      // [d][kpos]

    bf8_t qf[2][4];
#pragma unroll
    for (int qg = 0; qg < 2; qg++) {
        const int jqv = qg ? jq1 : jq0;
        const u16* Qrow = qkv + ((size_t)(b * 2048 + jqv * 64 + wave * 16 + lm)) * 6144 + h * 128;
#pragma unroll
        for (int ks = 0; ks < 4; ks++)
            qf[qg][ks] = *(const bf8_t*)(Qrow + ks * 32 + lq * 8);
    }

    f32x4 Of[2][8] = {};
    float mrun[2] = {-3.0e38f, -3.0e38f}, lrun[2] = {0.f, 0.f};

    const u16* Kbase = qkv + (size_t)b * 2048 * 6144 + 2048 + h * 128;
    const u16* VTbase = VT + (size_t)bh * 128 * 2048;

    const int krow = tid >> 4;        // 0..15
    const int kcol = (tid & 15) * 8;
    const int vrow = tid >> 3;        // 0..31
    const int vcol = (tid & 7) * 8;

    us8 kreg[4], vreg[4];
#pragma unroll
    for (int p = 0; p < 4; p++) {
        kreg[p] = *(const us8*)(Kbase + (size_t)(p * 16 + krow) * 6144 + kcol);
        vreg[p] = *(const us8*)(VTbase + (size_t)(p * 32 + vrow) * 2048 + vcol);
    }

    for (int kt = 0; kt <= ktmax; kt++) {
        __syncthreads();
#pragma unroll
        for (int p = 0; p < 4; p++) {
            *(us8*)&Kt[(p * 16 + krow) * 136 + kcol] = kreg[p];
            *(us8*)&Vt[(p * 32 + vrow) * 72 + vcol] = vreg[p];
        }
        __syncthreads();
        {   // prefetch next tile (clamped; final redundant reload discarded)
            int kn = (kt + 1 <= ktmax ? kt + 1 : ktmax) * 64;
#pragma unroll
            for (int p = 0; p < 4; p++) {
                kreg[p] = *(const us8*)(Kbase + (size_t)(kn + p * 16 + krow) * 6144 + kcol);
                vreg[p] = *(const us8*)(VTbase + (size_t)(p * 32 + vrow) * 2048 + kn + vcol);
            }
        }

        const bool act1 = (kt <= jq1);
        u64 pk[2][4];
#pragma unroll
        for (int qg = 0; qg < 2; qg++) {
            if (qg == 0 || act1) {
                const int jqv = qg ? jq1 : jq0;
                float sv[4][4];
#pragma unroll
                for (int nb = 0; nb < 4; nb++) {
                    f32x4 a = {};
#pragma unroll
                    for (int ks = 0; ks < 4; ks++) {
                        bf8_t kf = *(const bf8_t*)&Kt[(nb * 16 + lm) * 136 + ks * 32 + lq * 8];
                        a = mfma16(kf, qf[qg][ks], a);
                    }
#pragma unroll
                    for (int r = 0; r < 4; r++) sv[nb][r] = a[r] * ATT_SCALE;
                }
                if (kt == jqv) {
                    int qglob = jqv * 64 + wave * 16 + lm;
#pragma unroll
                    for (int nb = 0; nb < 4; nb++)
#pragma unroll
                        for (int r = 0; r < 4; r++)
                            if (kt * 64 + nb * 16 + lq * 4 + r > qglob) sv[nb][r] = -3.0e38f;
                }
                float mx = -3.0e38f;
#pragma unroll
                for (int nb = 0; nb < 4; nb++)
#pragma unroll
                    for (int r = 0; r < 4; r++) mx = fmaxf(mx, sv[nb][r]);
                mx = fmaxf(mx, __shfl_xor(mx, 16, 64));
                mx = fmaxf(mx, __shfl_xor(mx, 32, 64));
                float mnew = fmaxf(mrun[qg], mx);
                float a_ = __expf(mrun[qg] - mnew);
                float rs = 0.f;
#pragma unroll
                for (int nb = 0; nb < 4; nb++) {
                    float e0 = __expf(sv[nb][0] - mnew), e1 = __expf(sv[nb][1] - mnew);
                    float e2 = __expf(sv[nb][2] - mnew), e3 = __expf(sv[nb][3] - mnew);
                    rs += (e0 + e1) + (e2 + e3);
                    unsigned int lo = (unsigned int)f2b(e0) | ((unsigned int)f2b(e1) << 16);
                    unsigned int hi = (unsigned int)f2b(e2) | ((unsigned int)f2b(e3) << 16);
                    pk[qg][nb] = (u64)lo | ((u64)hi << 32);
                }
                rs += __shfl_xor(rs, 16, 64);
                rs += __shfl_xor(rs, 32, 64);
                lrun[qg] = lrun[qg] * a_ + rs;
                mrun[qg] = mnew;
#pragma unroll
                for (int db = 0; db < 8; db++)
#pragma unroll
                    for (int r = 0; r < 4; r++) Of[qg][db][r] *= a_;
            }
        }

        const int slo = ((lq & 1) * 2) * 16 + lm;
        const int shi = slo + 16;
        const bool sel = (lq >> 1) != 0;
#pragma unroll
        for (int kk = 0; kk < 2; kk++) {
            union { u64 v[2]; bf8_t f; } pf[2];
#pragma unroll
            for (int qg = 0; qg < 2; qg++) {
                if (qg == 0 || act1) {
                    u64 lo0 = __shfl(pk[qg][2 * kk + 0], slo, 64);
                    u64 lo1 = __shfl(pk[qg][2 * kk + 1], slo, 64);
                    u64 hi0 = __shfl(pk[qg][2 * kk + 0], shi, 64);
                    u64 hi1 = __shfl(pk[qg][2 * kk + 1], shi, 64);
                    pf[qg].v[0] = sel ? lo1 : lo0;
                    pf[qg].v[1] = sel ? hi1 : hi0;
                }
            }
#pragma unroll
            for (int db = 0; db < 8; db++) {
                bf8_t vf = *(const bf8_t*)&Vt[(db * 16 + lm) * 72 + kk * 32 + lq * 8];
                Of[0][db] = mfma16(vf, pf[0].f, Of[0][db]);
                if (act1) Of[1][db] = mfma16(vf, pf[1].f, Of[1][db]);
            }
        }
    }
#pragma unroll
    for (int qg = 0; qg < 2; qg++) {
        const int jqv = qg ? jq1 : jq0;
        float invl = 1.f / lrun[qg];
        size_t rowbase = (size_t)(b * 2048 + jqv * 64 + wave * 16 + lm) * 2048 + h * 128;
#pragma unroll
        for (int db = 0; db < 8; db++) {
            ushort4 o;
            o.x = f2b(Of[qg][db][0] * invl);
            o.y = f2b(Of[qg][db][1] * invl);
            o.z = f2b(Of[qg][db][2] * invl);
            o.w = f2b(Of[qg][db][3] * invl);
            *(ushort4*)(AO + rowbase + db * 16 + lq * 4) = o;
        }
    }
}

extern "C" void kernel_launch(void* const* d_in, const int* in_sizes, int n_in,
                              void* d_out, int out_size, void* d_ws, size_t ws_size,
                              hipStream_t stream) {
    const float* x     = (const float*)d_in[0];
    const float* w_qkv = (const float*)d_in[1];
    const float* w_o   = (const float*)d_in[2];
    float* out = (float*)d_out;
    u16* ws = (u16*)d_ws;

    u16* qkvb  = ws;                    // 25,165,824
    u16* VT    = ws + 25165824;         //  8,388,608
    u16* AO    = ws + 33554432;         //  8,388,608
    u16* xb    = ws + 41943040;         //  8,388,608
    u16* wqkvb = ws + 50331648;         // 12,582,912
    u16* wob   = ws + 62914560;         //  4,194,304

    f32_to_bf16<<<4096, 256, 0, stream>>>(x, xb, 1048576);
    f32_to_bf16<<<6144, 256, 0, stream>>>(w_qkv, wqkvb, 1572864);
    f32_to_bf16<<<2048, 256, 0, stream>>>(w_o, wob, 524288);
    gemm256<0><<<384, 512, 0, stream>>>(xb, wqkvb, qkvb, 6144);     // QKV: 16x24 tiles
    rope_vt<<<dim3(32, 32), 256, 0, stream>>>(qkvb, VT);
    attn_flash<<<dim3(512), 256, 0, stream>>>(qkvb, VT, AO);
    gemm256<1><<<128, 512, 0, stream>>>(AO, wob, out, 2048);        // out: 16x8 tiles
}

// Round 5
// 416.098 us; speedup vs baseline: 1.0916x; 1.0916x over previous
//
#include <hip/hip_runtime.h>
#include <hip/hip_bf16.h>

typedef unsigned short u16;
typedef unsigned long long u64;
typedef u16 us8 __attribute__((ext_vector_type(8)));
typedef __bf16 bf8_t __attribute__((ext_vector_type(8)));
typedef float f32x4 __attribute__((ext_vector_type(4)));

__device__ __forceinline__ float b2f(u16 u) {
    return __uint_as_float(((unsigned int)u) << 16);
}
__device__ __forceinline__ u16 f2b(float f) {
    union { __hip_bfloat16 h; u16 u; } v;
    v.h = __float2bfloat16(f);
    return v.u;
}
__device__ __forceinline__ f32x4 mfma16(bf8_t a, bf8_t b, f32x4 c) {
    return __builtin_amdgcn_mfma_f32_16x16x32_bf16(a, b, c, 0, 0, 0);
}
__device__ __forceinline__ void gload_lds16(const u16* g, u16* lds_base) {
    __builtin_amdgcn_global_load_lds((const __attribute__((address_space(1))) unsigned int*)g,
                                     (__attribute__((address_space(3))) unsigned int*)lds_base,
                                     16, 0, 0);
}

// ---------------- fp32 -> bf16 convert (8 elems/thread)
__global__ __launch_bounds__(256) void f32_to_bf16(const float* __restrict__ src,
                                                   u16* __restrict__ dst, int n8) {
    int idx = blockIdx.x * 256 + threadIdx.x;
    if (idx >= n8) return;
    float4 f0 = ((const float4*)src)[idx * 2];
    float4 f1 = ((const float4*)src)[idx * 2 + 1];
    us8 o;
    o[0] = f2b(f0.x); o[1] = f2b(f0.y); o[2] = f2b(f0.z); o[3] = f2b(f0.w);
    o[4] = f2b(f1.x); o[5] = f2b(f1.y); o[6] = f2b(f1.z); o[7] = f2b(f1.w);
    ((us8*)dst)[idx] = o;
}

// ---------------- 8-phase pipelined GEMM, 3-bit LDS chunk swizzle.
// C[m,n] = sum_k A[m,k]*B[n,k]; K=2048 fixed (32 k-tiles of BK=64).
// AH=2: BM=256 (8 m-frags/wave); AH=1: BM=128 (4 m-frags/wave). BN=256 always.
// 512 threads = 8 waves (2M x 4N). LDS: A 2x(AH*16KB) + B 2x32KB.
// Swizzle (G4): LDS[row][chunk q] holds G[row][q ^ (row&7)] (16B chunks);
// frag read XORs chunk with (lm&7) -> every read spreads 8 lanes per bank-group
// (2 lanes/bank = free). Stage side: linear global_load_lds dest, per-lane
// global source chunk = (lane&7)^(lane>>3) (rule #21 involution).
// Phases per k-tile: {ds-reads | 1 half-tile stage | bar | lgkm0 | MFMA quad | bar};
// stage B(t+1)->other buf in ph1/2, A(t+2)->own buf in ph3(/4).
// vmcnt counted once per tile (AH=2: 4, AH=1: 2) - never drained to 0.
#define BARX() __builtin_amdgcn_s_barrier()
#define LGKM0() do { asm volatile("s_waitcnt lgkmcnt(0)" ::: "memory"); \
                     __builtin_amdgcn_sched_barrier(0); } while (0)
#define VMN() do { \
    if constexpr (AH == 2) asm volatile("s_waitcnt vmcnt(4)" ::: "memory"); \
    else                   asm volatile("s_waitcnt vmcnt(2)" ::: "memory"); \
    __builtin_amdgcn_sched_barrier(0); } while (0)

template<int SF32, int AH>
__global__ __launch_bounds__(512, 2) void gemm256(const u16* __restrict__ A,
                                                  const u16* __restrict__ B,
                                                  void* __restrict__ Cout, int ldc) {
    constexpr int MF = AH * 4;          // m-frags per wave
    constexpr int MH = AH * 2;          // m-frags per quadrant

    __shared__ u16 LA[2][AH * 128 * 64];
    __shared__ u16 LB[2][256 * 64];

    const int tid = threadIdx.x;
    const int w = tid >> 6, lane = tid & 63;
    const int lm = lane & 15, lq = lane >> 4;
    const int wm = w >> 2, wn = w & 3;          // 2M x 4N wave grid

    // XCD-aware bijective swizzle (grid % 8 == 0): consecutive wg per XCD share nt.
    const int bid = blockIdx.x;
    const int nper = gridDim.x >> 3;
    const int wg = (bid & 7) * nper + (bid >> 3);
    const int mt = (AH == 2) ? (wg & 15) : (wg & 31);
    const int nt = (AH == 2) ? (wg >> 4) : (wg >> 5);
    const int m0 = mt * (AH * 128), n0 = nt * 256;

    // staging source: lane covers row (lane>>3) of an 8-row slice, global 16B
    // chunk (lane&7)^(lane>>3) -> linear LDS dest lands G4-swizzled.
    const int srow = lane >> 3;                 // 0..7
    const int scol = ((lane & 7) ^ srow) * 8;   // u16 col

    const u16* Ag = A + (size_t)(m0 + srow) * 2048 + scol;
    const u16* Bg = B + (size_t)(n0 + srow) * 2048 + scol;

#define STAGE_A(c, h, kt) do { \
    _Pragma("unroll") \
    for (int i = 0; i < 2; i++) { \
        int R = w * 2 + i; \
        gload_lds16(Ag + (size_t)((h) * 128 + R * 8) * 2048 + (kt) * 64, \
                    &LA[c][((h) * 128 + R * 8) * 64]); \
    } } while (0)

#define STAGE_B(c, h, kt) do { \
    _Pragma("unroll") \
    for (int i = 0; i < 2; i++) { \
        int R = w * 2 + i; \
        gload_lds16(Bg + (size_t)((h) * 128 + R * 8) * 2048 + (kt) * 64, \
                    &LB[c][((h) * 128 + R * 8) * 64]); \
    } } while (0)

    bf8_t af[MF][2], bfr[4][2];
    f32x4 acc[MF][4] = {};
    const int cswz = (lm & 7) << 4;             // row&7 == lm&7 for all frag rows

#define RD_A(c, mh) do { \
    _Pragma("unroll") \
    for (int m = 0; m < MH; m++) \
    _Pragma("unroll") \
    for (int ks = 0; ks < 2; ks++) { \
        int row = wm * (AH * 64) + ((mh) * MH + m) * 16 + lm; \
        int o = (row * 128 + ks * 64 + lq * 16) ^ cswz; \
        af[(mh) * MH + m][ks] = *(const bf8_t*)((const char*)&LA[c][0] + o); \
    } } while (0)

#define RD_B(c, nh) do { \
    _Pragma("unroll") \
    for (int n = 0; n < 2; n++) \
    _Pragma("unroll") \
    for (int ks = 0; ks < 2; ks++) { \
        int row = wn * 64 + ((nh) * 2 + n) * 16 + lm; \
        int o = (row * 128 + ks * 64 + lq * 16) ^ cswz; \
        bfr[(nh) * 2 + n][ks] = *(const bf8_t*)((const char*)&LB[c][0] + o); \
    } } while (0)

#define QUAD(mh, nh) do { \
    __builtin_amdgcn_s_setprio(1); \
    _Pragma("unroll") \
    for (int m = 0; m < MH; m++) \
    _Pragma("unroll") \
    for (int n = 0; n < 2; n++) \
    _Pragma("unroll") \
    for (int ks = 0; ks < 2; ks++) \
        acc[(mh) * MH + m][(nh) * 2 + n] = mfma16(af[(mh) * MH + m][ks], \
            bfr[(nh) * 2 + n][ks], acc[(mh) * MH + m][(nh) * 2 + n]); \
    __builtin_amdgcn_s_setprio(0); \
    } while (0)

#define TILE(c, tB, tA) do { \
    RD_A(c, 0); RD_B(c, 0); \
    STAGE_B((c) ^ 1, 0, tB); \
    BARX(); LGKM0(); \
    QUAD(0, 0); \
    BARX(); \
    RD_A(c, 1); \
    STAGE_B((c) ^ 1, 1, tB); \
    BARX(); LGKM0(); \
    QUAD(1, 0); \
    BARX(); \
    RD_B(c, 1); \
    STAGE_A(c, 0, tA); \
    BARX(); LGKM0(); \
    QUAD(0, 1); \
    BARX(); \
    if constexpr (AH == 2) STAGE_A(c, 1, tA); \
    QUAD(1, 1); \
    VMN(); \
    BARX(); \
} while (0)

    // prologue: tile0 A+B -> buf0, tile1 A -> buf1; VMN leaves A(1) in flight.
    STAGE_A(0, 0, 0);
    if constexpr (AH == 2) STAGE_A(0, 1, 0);
    STAGE_B(0, 0, 0); STAGE_B(0, 1, 0);
    STAGE_A(1, 0, 1);
    if constexpr (AH == 2) STAGE_A(1, 1, 1);
    VMN();
    BARX();

    for (int it = 0; it < 16; it++) {
        const int t0 = 2 * it, t1 = 2 * it + 1;
        const int tB0 = t1;                              // B(t0+1)
        const int tA0 = (t0 + 2 < 32) ? t0 + 2 : 31;     // clamped dummy at tail
        const int tB1 = (t1 + 1 < 32) ? t1 + 1 : 31;
        const int tA1 = (t1 + 2 < 32) ? t1 + 2 : 31;
        TILE(0, tB0, tA0);
        TILE(1, tB1, tA1);
    }

    // epilogue
#pragma unroll
    for (int m = 0; m < MF; m++)
#pragma unroll
        for (int n = 0; n < 4; n++)
#pragma unroll
            for (int r = 0; r < 4; r++) {
                int row = m0 + wm * (AH * 64) + m * 16 + lq * 4 + r;
                int col = n0 + wn * 64 + n * 16 + lm;
                if (SF32)
                    ((float*)Cout)[(size_t)row * ldc + col] = acc[m][n][r];
                else
                    ((u16*)Cout)[(size_t)row * ldc + col] = f2b(acc[m][n][r]);
            }
#undef TILE
#undef QUAD
#undef RD_A
#undef RD_B
#undef STAGE_A
#undef STAGE_B
}

// ---------------- Fused: RoPE in-place on Q,K  +  V transpose -> VT (B,H,D,S)
__global__ __launch_bounds__(256) void rope_vt(u16* __restrict__ qkv, u16* __restrict__ VT) {
    __shared__ u16 T[64 * 136];
    const int tid = threadIdx.x;
    const int s0 = blockIdx.x * 64;
    const int bh = blockIdx.y;
    const int b = bh >> 4, h = bh & 15;
#pragma unroll
    for (int p = 0; p < 4; p++) {
        int sl = p * 16 + (tid >> 4);
        int d0 = (tid & 15) * 8;
        *(us8*)&T[sl * 136 + d0] =
            *(const us8*)(qkv + ((size_t)(b * 2048 + s0 + sl)) * 6144 + 4096 + h * 128 + d0);
    }
#pragma unroll
    for (int p = 0; p < 2; p++) {
        int task = p * 256 + tid;
        int sl = task >> 3;
        int jg = task & 7;
        size_t base = ((size_t)(b * 2048 + s0 + sl)) * 6144 + h * 128 + jg * 8;
        us8 qlo = *(const us8*)(qkv + base);
        us8 qhi = *(const us8*)(qkv + base + 64);
        us8 klo = *(const us8*)(qkv + base + 2048);
        us8 khi = *(const us8*)(qkv + base + 2048 + 64);
        us8 oql, oqh, okl, okh;
        float s = (float)(s0 + sl);
#pragma unroll
        for (int e = 0; e < 8; e++) {
            int j = jg * 8 + e;
            float inv = __expf((float)j * (-9.210340371976184f / 64.f));
            float ang = s * inv;
            float sn, c;
            __sincosf(ang, &sn, &c);
            float q1 = b2f(qlo[e]), q2 = b2f(qhi[e]);
            oql[e] = f2b(q1 * c - q2 * sn);
            oqh[e] = f2b(q2 * c + q1 * sn);
            float k1 = b2f(klo[e]), k2 = b2f(khi[e]);
            okl[e] = f2b(k1 * c - k2 * sn);
            okh[e] = f2b(k2 * c + k1 * sn);
        }
        *(us8*)(qkv + base) = oql;
        *(us8*)(qkv + base + 64) = oqh;
        *(us8*)(qkv + base + 2048) = okl;
        *(us8*)(qkv + base + 2048 + 64) = okh;
    }
    __syncthreads();
#pragma unroll
    for (int p = 0; p < 4; p++) {
        int idx = p * 256 + tid;
        int d = idx & 127;
        int sg = idx >> 7;
        us8 v;
#pragma unroll
        for (int i = 0; i < 8; i++) v[i] = T[(sg * 8 + i) * 136 + d];
        *(us8*)&VT[((size_t)bh * 128 + d) * 2048 + s0 + sg * 8] = v;
    }
}

// ---------------- Flash attention v5: balanced causal pairing (33 qg-tile units/block).
#define ATT_SCALE 0.08838834764831845f

__global__ __launch_bounds__(256, 2) void attn_flash(const u16* __restrict__ qkv, const u16* __restrict__ VT,
                                                     u16* __restrict__ AO) {
    const int bid = blockIdx.x;
    const int swz = (bid & 7) * 64 + (bid >> 3);
    const int bh = swz >> 4;          // 0..31
    const int pair = swz & 15;        // 0..15
    const int b = bh >> 4, h = bh & 15;
    const int tid = threadIdx.x, lane = tid & 63, wave = tid >> 6;
    const int lm = lane & 15, lq = lane >> 4;

    const int jq0 = 31 - pair;        // high q-subtile (64-row units), always active
    const int jq1 = pair;             // low q-subtile, active for kt <= jq1
    const int ktmax = jq0;

    __shared__ u16 Kt[64 * 136];      // [kpos][d]
    __shared__ u16 Vt[128 * 72];      // [d][kpos]

    bf8_t qf[2][4];
#pragma unroll
    for (int qg = 0; qg < 2; qg++) {
        const int jqv = qg ? jq1 : jq0;
        const u16* Qrow = qkv + ((size_t)(b * 2048 + jqv * 64 + wave * 16 + lm)) * 6144 + h * 128;
#pragma unroll
        for (int ks = 0; ks < 4; ks++)
            qf[qg][ks] = *(const bf8_t*)(Qrow + ks * 32 + lq * 8);
    }

    f32x4 Of[2][8] = {};
    float mrun[2] = {-3.0e38f, -3.0e38f}, lrun[2] = {0.f, 0.f};

    const u16* Kbase = qkv + (size_t)b * 2048 * 6144 + 2048 + h * 128;
    const u16* VTbase = VT + (size_t)bh * 128 * 2048;

    const int krow = tid >> 4;        // 0..15
    const int kcol = (tid & 15) * 8;
    const int vrow = tid >> 3;        // 0..31
    const int vcol = (tid & 7) * 8;

    us8 kreg[4], vreg[4];
#pragma unroll
    for (int p = 0; p < 4; p++) {
        kreg[p] = *(const us8*)(Kbase + (size_t)(p * 16 + krow) * 6144 + kcol);
        vreg[p] = *(const us8*)(VTbase + (size_t)(p * 32 + vrow) * 2048 + vcol);
    }

    for (int kt = 0; kt <= ktmax; kt++) {
        __syncthreads();
#pragma unroll
        for (int p = 0; p < 4; p++) {
            *(us8*)&Kt[(p * 16 + krow) * 136 + kcol] = kreg[p];
            *(us8*)&Vt[(p * 32 + vrow) * 72 + vcol] = vreg[p];
        }
        __syncthreads();
        {   // prefetch next tile (clamped; final redundant reload discarded)
            int kn = (kt + 1 <= ktmax ? kt + 1 : ktmax) * 64;
#pragma unroll
            for (int p = 0; p < 4; p++) {
                kreg[p] = *(const us8*)(Kbase + (size_t)(kn + p * 16 + krow) * 6144 + kcol);
                vreg[p] = *(const us8*)(VTbase + (size_t)(p * 32 + vrow) * 2048 + kn + vcol);
            }
        }

        const bool act1 = (kt <= jq1);
        u64 pk[2][4];
#pragma unroll
        for (int qg = 0; qg < 2; qg++) {
            if (qg == 0 || act1) {
                const int jqv = qg ? jq1 : jq0;
                float sv[4][4];
#pragma unroll
                for (int nb = 0; nb < 4; nb++) {
                    f32x4 a = {};
#pragma unroll
                    for (int ks = 0; ks < 4; ks++) {
                        bf8_t kf = *(const bf8_t*)&Kt[(nb * 16 + lm) * 136 + ks * 32 + lq * 8];
                        a = mfma16(kf, qf[qg][ks], a);
                    }
#pragma unroll
                    for (int r = 0; r < 4; r++) sv[nb][r] = a[r] * ATT_SCALE;
                }
                if (kt == jqv) {
                    int qglob = jqv * 64 + wave * 16 + lm;
#pragma unroll
                    for (int nb = 0; nb < 4; nb++)
#pragma unroll
                        for (int r = 0; r < 4; r++)
                            if (kt * 64 + nb * 16 + lq * 4 + r > qglob) sv[nb][r] = -3.0e38f;
                }
                float mx = -3.0e38f;
#pragma unroll
                for (int nb = 0; nb < 4; nb++)
#pragma unroll
                    for (int r = 0; r < 4; r++) mx = fmaxf(mx, sv[nb][r]);
                mx = fmaxf(mx, __shfl_xor(mx, 16, 64));
                mx = fmaxf(mx, __shfl_xor(mx, 32, 64));
                float mnew = fmaxf(mrun[qg], mx);
                float a_ = __expf(mrun[qg] - mnew);
                float rs = 0.f;
#pragma unroll
                for (int nb = 0; nb < 4; nb++) {
                    float e0 = __expf(sv[nb][0] - mnew), e1 = __expf(sv[nb][1] - mnew);
                    float e2 = __expf(sv[nb][2] - mnew), e3 = __expf(sv[nb][3] - mnew);
                    rs += (e0 + e1) + (e2 + e3);
                    unsigned int lo = (unsigned int)f2b(e0) | ((unsigned int)f2b(e1) << 16);
                    unsigned int hi = (unsigned int)f2b(e2) | ((unsigned int)f2b(e3) << 16);
                    pk[qg][nb] = (u64)lo | ((u64)hi << 32);
                }
                rs += __shfl_xor(rs, 16, 64);
                rs += __shfl_xor(rs, 32, 64);
                lrun[qg] = lrun[qg] * a_ + rs;
                mrun[qg] = mnew;
#pragma unroll
                for (int db = 0; db < 8; db++)
#pragma unroll
                    for (int r = 0; r < 4; r++) Of[qg][db][r] *= a_;
            }
        }

        const int slo = ((lq & 1) * 2) * 16 + lm;
        const int shi = slo + 16;
        const bool sel = (lq >> 1) != 0;
#pragma unroll
        for (int kk = 0; kk < 2; kk++) {
            union { u64 v[2]; bf8_t f; } pf[2];
#pragma unroll
            for (int qg = 0; qg < 2; qg++) {
                if (qg == 0 || act1) {
                    u64 lo0 = __shfl(pk[qg][2 * kk + 0], slo, 64);
                    u64 lo1 = __shfl(pk[qg][2 * kk + 1], slo, 64);
                    u64 hi0 = __shfl(pk[qg][2 * kk + 0], shi, 64);
                    u64 hi1 = __shfl(pk[qg][2 * kk + 1], shi, 64);
                    pf[qg].v[0] = sel ? lo1 : lo0;
                    pf[qg].v[1] = sel ? hi1 : hi0;
                }
            }
#pragma unroll
            for (int db = 0; db < 8; db++) {
                bf8_t vf = *(const bf8_t*)&Vt[(db * 16 + lm) * 72 + kk * 32 + lq * 8];
                Of[0][db] = mfma16(vf, pf[0].f, Of[0][db]);
                if (act1) Of[1][db] = mfma16(vf, pf[1].f, Of[1][db]);
            }
        }
    }
#pragma unroll
    for (int qg = 0; qg < 2; qg++) {
        const int jqv = qg ? jq1 : jq0;
        float invl = 1.f / lrun[qg];
        size_t rowbase = (size_t)(b * 2048 + jqv * 64 + wave * 16 + lm) * 2048 + h * 128;
#pragma unroll
        for (int db = 0; db < 8; db++) {
            ushort4 o;
            o.x = f2b(Of[qg][db][0] * invl);
            o.y = f2b(Of[qg][db][1] * invl);
            o.z = f2b(Of[qg][db][2] * invl);
            o.w = f2b(Of[qg][db][3] * invl);
            *(ushort4*)(AO + rowbase + db * 16 + lq * 4) = o;
        }
    }
}

extern "C" void kernel_launch(void* const* d_in, const int* in_sizes, int n_in,
                              void* d_out, int out_size, void* d_ws, size_t ws_size,
                              hipStream_t stream) {
    const float* x     = (const float*)d_in[0];
    const float* w_qkv = (const float*)d_in[1];
    const float* w_o   = (const float*)d_in[2];
    float* out = (float*)d_out;
    u16* ws = (u16*)d_ws;

    u16* qkvb  = ws;                    // 25,165,824
    u16* VT    = ws + 25165824;         //  8,388,608
    u16* AO    = ws + 33554432;         //  8,388,608
    u16* xb    = ws + 41943040;         //  8,388,608
    u16* wqkvb = ws + 50331648;         // 12,582,912
    u16* wob   = ws + 62914560;         //  4,194,304

    f32_to_bf16<<<4096, 256, 0, stream>>>(x, xb, 1048576);
    f32_to_bf16<<<6144, 256, 0, stream>>>(w_qkv, wqkvb, 1572864);
    f32_to_bf16<<<2048, 256, 0, stream>>>(w_o, wob, 524288);
    gemm256<0, 2><<<384, 512, 0, stream>>>(xb, wqkvb, qkvb, 6144);  // QKV: 16x24 (BM=256)
    rope_vt<<<dim3(32, 32), 256, 0, stream>>>(qkvb, VT);
    attn_flash<<<dim3(512), 256, 0, stream>>>(qkvb, VT, AO);
    gemm256<1, 1><<<256, 512, 0, stream>>>(AO, wob, out, 2048);     // out: 32x8 (BM=128)
}

// Round 6
// 380.611 us; speedup vs baseline: 1.1933x; 1.0932x over previous
//
#include <hip/hip_runtime.h>
#include <hip/hip_bf16.h>

typedef unsigned short u16;
typedef unsigned long long u64;
typedef u16 us8 __attribute__((ext_vector_type(8)));
typedef __bf16 bf8_t __attribute__((ext_vector_type(8)));
typedef float f32x4 __attribute__((ext_vector_type(4)));

__device__ __forceinline__ float b2f(u16 u) {
    return __uint_as_float(((unsigned int)u) << 16);
}
__device__ __forceinline__ u16 f2b(float f) {
    union { __hip_bfloat16 h; u16 u; } v;
    v.h = __float2bfloat16(f);
    return v.u;
}
__device__ __forceinline__ f32x4 mfma16(bf8_t a, bf8_t b, f32x4 c) {
    return __builtin_amdgcn_mfma_f32_16x16x32_bf16(a, b, c, 0, 0, 0);
}
__device__ __forceinline__ void gload_lds16(const u16* g, u16* lds_base) {
    __builtin_amdgcn_global_load_lds((const __attribute__((address_space(1))) unsigned int*)g,
                                     (__attribute__((address_space(3))) unsigned int*)lds_base,
                                     16, 0, 0);
}

// ---------------- fp32 -> bf16 convert (8 elems/thread)
__global__ __launch_bounds__(256) void f32_to_bf16(const float* __restrict__ src,
                                                   u16* __restrict__ dst, int n8) {
    int idx = blockIdx.x * 256 + threadIdx.x;
    if (idx >= n8) return;
    float4 f0 = ((const float4*)src)[idx * 2];
    float4 f1 = ((const float4*)src)[idx * 2 + 1];
    us8 o;
    o[0] = f2b(f0.x); o[1] = f2b(f0.y); o[2] = f2b(f0.z); o[3] = f2b(f0.w);
    o[4] = f2b(f1.x); o[5] = f2b(f1.y); o[6] = f2b(f1.z); o[7] = f2b(f1.w);
    ((us8*)dst)[idx] = o;
}

#define BARX() __builtin_amdgcn_s_barrier()
#define LGKM0() do { asm volatile("s_waitcnt lgkmcnt(0)" ::: "memory"); \
                     __builtin_amdgcn_sched_barrier(0); } while (0)
#define VM4A()  do { asm volatile("s_waitcnt vmcnt(4)" ::: "memory"); \
                     __builtin_amdgcn_sched_barrier(0); } while (0)

// ---------------- QKV GEMM: BM=256 x BN=192, BK=64, grid 16x32=512 (exactly 2
// rounds on 256 CUs). 8 waves as 4M x 2N; per-wave 64x96 (MF=4 m-frags, NF=6
// n-frags). LDS 112KB: A 2x32KB + B 2x24KB. 3 phases/tile, 16 MFMA each.
// Reads 12/4/4 per phase; stage B(t+1) (3 thirds) ph1, A(t+2) (2+2 chunks)
// ph2/ph3; vmcnt(4) once per tile (A(t+2) stays in flight). 3-bit chunk
// swizzle identical to round-5 (conflict-free, measured 0).
__global__ __launch_bounds__(512, 2) void gemm192(const u16* __restrict__ A,
                                                  const u16* __restrict__ B,
                                                  u16* __restrict__ Cout, int ldc) {
    __shared__ u16 LA[2][256 * 64];
    __shared__ u16 LB[2][192 * 64];

    const int tid = threadIdx.x;
    const int w = tid >> 6, lane = tid & 63;
    const int lm = lane & 15, lq = lane >> 4;
    const int wm = w >> 1, wn = w & 1;          // 4M x 2N wave grid

    const int bid = blockIdx.x;
    const int nper = gridDim.x >> 3;            // 64
    const int wg = (bid & 7) * nper + (bid >> 3);
    const int mt = wg & 15, nt = wg >> 4;       // 16 x 32
    const int m0 = mt * 256, n0 = nt * 192;

    const int srow = lane >> 3;                 // 0..7
    const int scol = ((lane & 7) ^ srow) * 8;   // pre-swizzled source chunk

    const u16* Ag = A + (size_t)(m0 + srow) * 2048 + scol;
    const u16* Bg = B + (size_t)(n0 + srow) * 2048 + scol;

#define STAGE_A2(c, kt, jb) do { \
    _Pragma("unroll") \
    for (int j = 0; j < 2; j++) { \
        int R = ((jb) + j) * 64 + w * 8; \
        gload_lds16(Ag + (size_t)R * 2048 + (kt) * 64, &LA[c][R * 64]); \
    } } while (0)

#define STAGE_B3(c, kt) do { \
    _Pragma("unroll") \
    for (int j = 0; j < 3; j++) { \
        int R = j * 64 + w * 8; \
        gload_lds16(Bg + (size_t)R * 2048 + (kt) * 64, &LB[c][R * 64]); \
    } } while (0)

    bf8_t af[4][2], bfr[6][2];
    f32x4 acc[4][6] = {};
    const int cswz = (lm & 7) << 4;

#define RD_A4(c) do { \
    _Pragma("unroll") \
    for (int m = 0; m < 4; m++) \
    _Pragma("unroll") \
    for (int ks = 0; ks < 2; ks++) { \
        int row = wm * 64 + m * 16 + lm; \
        int o = (row * 128 + ks * 64 + lq * 16) ^ cswz; \
        af[m][ks] = *(const bf8_t*)((const char*)&LA[c][0] + o); \
    } } while (0)

#define RD_B2(c, np) do { \
    _Pragma("unroll") \
    for (int n = 0; n < 2; n++) \
    _Pragma("unroll") \
    for (int ks = 0; ks < 2; ks++) { \
        int row = wn * 96 + ((np) * 2 + n) * 16 + lm; \
        int o = (row * 128 + ks * 64 + lq * 16) ^ cswz; \
        bfr[(np) * 2 + n][ks] = *(const bf8_t*)((const char*)&LB[c][0] + o); \
    } } while (0)

#define QUAD6(np) do { \
    __builtin_amdgcn_s_setprio(1); \
    _Pragma("unroll") \
    for (int m = 0; m < 4; m++) \
    _Pragma("unroll") \
    for (int n = 0; n < 2; n++) \
    _Pragma("unroll") \
    for (int ks = 0; ks < 2; ks++) \
        acc[m][(np) * 2 + n] = mfma16(af[m][ks], bfr[(np) * 2 + n][ks], \
                                      acc[m][(np) * 2 + n]); \
    __builtin_amdgcn_s_setprio(0); \
    } while (0)

#define TILE192(c, tB, tA) do { \
    RD_A4(c); RD_B2(c, 0); \
    STAGE_B3((c) ^ 1, tB); \
    BARX(); LGKM0(); \
    QUAD6(0); \
    BARX(); \
    RD_B2(c, 1); \
    STAGE_A2(c, tA, 0); \
    BARX(); LGKM0(); \
    QUAD6(1); \
    BARX(); \
    RD_B2(c, 2); \
    STAGE_A2(c, tA, 2); \
    BARX(); LGKM0(); \
    QUAD6(2); \
    VM4A(); \
    BARX(); \
} while (0)

    // prologue: A(0)x4, B(0)x3 -> buf0; A(1)x4 -> buf1. VM4 leaves A(1) in flight.
    STAGE_A2(0, 0, 0); STAGE_A2(0, 0, 2);
    STAGE_B3(0, 0);
    STAGE_A2(1, 1, 0); STAGE_A2(1, 1, 2);
    VM4A();
    BARX();

    for (int it = 0; it < 16; it++) {
        const int t0 = 2 * it, t1 = 2 * it + 1;
        const int tB0 = t1;
        const int tA0 = (t0 + 2 < 32) ? t0 + 2 : 31;
        const int tB1 = (t1 + 1 < 32) ? t1 + 1 : 31;
        const int tA1 = (t1 + 2 < 32) ? t1 + 2 : 31;
        TILE192(0, tB0, tA0);
        TILE192(1, tB1, tA1);
    }

#pragma unroll
    for (int m = 0; m < 4; m++)
#pragma unroll
        for (int n = 0; n < 6; n++)
#pragma unroll
            for (int r = 0; r < 4; r++) {
                int row = m0 + wm * 64 + m * 16 + lq * 4 + r;
                int col = n0 + wn * 96 + n * 16 + lm;
                Cout[(size_t)row * ldc + col] = f2b(acc[m][n][r]);
            }
#undef TILE192
#undef QUAD6
#undef RD_A4
#undef RD_B2
#undef STAGE_A2
#undef STAGE_B3
}

// ---------------- out-proj GEMM (unchanged from round 5): BM=128 BN=256,
// grid 32x8 = 256 = exactly 1 round. 8 waves 2M x 4N, 4 phases/tile.
#define VMN() do { \
    asm volatile("s_waitcnt vmcnt(2)" ::: "memory"); \
    __builtin_amdgcn_sched_barrier(0); } while (0)

__global__ __launch_bounds__(512, 2) void gemm_op(const u16* __restrict__ A,
                                                  const u16* __restrict__ B,
                                                  float* __restrict__ Cout, int ldc) {
    __shared__ u16 LA[2][128 * 64];
    __shared__ u16 LB[2][256 * 64];

    const int tid = threadIdx.x;
    const int w = tid >> 6, lane = tid & 63;
    const int lm = lane & 15, lq = lane >> 4;
    const int wm = w >> 2, wn = w & 3;          // 2M x 4N

    const int bid = blockIdx.x;
    const int nper = gridDim.x >> 3;
    const int wg = (bid & 7) * nper + (bid >> 3);
    const int mt = wg & 31, nt = wg >> 5;
    const int m0 = mt * 128, n0 = nt * 256;

    const int srow = lane >> 3;
    const int scol = ((lane & 7) ^ srow) * 8;

    const u16* Ag = A + (size_t)(m0 + srow) * 2048 + scol;
    const u16* Bg = B + (size_t)(n0 + srow) * 2048 + scol;

#define STAGE_A(c, h, kt) do { \
    _Pragma("unroll") \
    for (int i = 0; i < 2; i++) { \
        int R = w * 2 + i; \
        if ((h) == 0) \
            gload_lds16(Ag + (size_t)(R * 8) * 2048 + (kt) * 64, &LA[c][(R * 8) * 64]); \
    } } while (0)

#define STAGE_B(c, h, kt) do { \
    _Pragma("unroll") \
    for (int i = 0; i < 2; i++) { \
        int R = w * 2 + i; \
        gload_lds16(Bg + (size_t)((h) * 128 + R * 8) * 2048 + (kt) * 64, \
                    &LB[c][((h) * 128 + R * 8) * 64]); \
    } } while (0)

    bf8_t af[4][2], bfr[4][2];
    f32x4 acc[4][4] = {};
    const int cswz = (lm & 7) << 4;

#define RD_A(c, mh) do { \
    _Pragma("unroll") \
    for (int m = 0; m < 2; m++) \
    _Pragma("unroll") \
    for (int ks = 0; ks < 2; ks++) { \
        int row = wm * 64 + ((mh) * 2 + m) * 16 + lm; \
        int o = (row * 128 + ks * 64 + lq * 16) ^ cswz; \
        af[(mh) * 2 + m][ks] = *(const bf8_t*)((const char*)&LA[c][0] + o); \
    } } while (0)

#define RD_B(c, nh) do { \
    _Pragma("unroll") \
    for (int n = 0; n < 2; n++) \
    _Pragma("unroll") \
    for (int ks = 0; ks < 2; ks++) { \
        int row = wn * 64 + ((nh) * 2 + n) * 16 + lm; \
        int o = (row * 128 + ks * 64 + lq * 16) ^ cswz; \
        bfr[(nh) * 2 + n][ks] = *(const bf8_t*)((const char*)&LB[c][0] + o); \
    } } while (0)

#define QUAD(mh, nh) do { \
    __builtin_amdgcn_s_setprio(1); \
    _Pragma("unroll") \
    for (int m = 0; m < 2; m++) \
    _Pragma("unroll") \
    for (int n = 0; n < 2; n++) \
    _Pragma("unroll") \
    for (int ks = 0; ks < 2; ks++) \
        acc[(mh) * 2 + m][(nh) * 2 + n] = mfma16(af[(mh) * 2 + m][ks], \
            bfr[(nh) * 2 + n][ks], acc[(mh) * 2 + m][(nh) * 2 + n]); \
    __builtin_amdgcn_s_setprio(0); \
    } while (0)

#define TILEOP(c, tB, tA) do { \
    RD_A(c, 0); RD_B(c, 0); \
    STAGE_B((c) ^ 1, 0, tB); \
    BARX(); LGKM0(); \
    QUAD(0, 0); \
    BARX(); \
    RD_A(c, 1); \
    STAGE_B((c) ^ 1, 1, tB); \
    BARX(); LGKM0(); \
    QUAD(1, 0); \
    BARX(); \
    RD_B(c, 1); \
    STAGE_A(c, 0, tA); \
    BARX(); LGKM0(); \
    QUAD(0, 1); \
    BARX(); \
    QUAD(1, 1); \
    VMN(); \
    BARX(); \
} while (0)

    STAGE_A(0, 0, 0);
    STAGE_B(0, 0, 0); STAGE_B(0, 1, 0);
    STAGE_A(1, 0, 1);
    VMN();
    BARX();

    for (int it = 0; it < 16; it++) {
        const int t0 = 2 * it, t1 = 2 * it + 1;
        const int tB0 = t1;
        const int tA0 = (t0 + 2 < 32) ? t0 + 2 : 31;
        const int tB1 = (t1 + 1 < 32) ? t1 + 1 : 31;
        const int tA1 = (t1 + 2 < 32) ? t1 + 2 : 31;
        TILEOP(0, tB0, tA0);
        TILEOP(1, tB1, tA1);
    }

#pragma unroll
    for (int m = 0; m < 4; m++)
#pragma unroll
        for (int n = 0; n < 4; n++)
#pragma unroll
            for (int r = 0; r < 4; r++) {
                int row = m0 + wm * 64 + m * 16 + lq * 4 + r;
                int col = n0 + wn * 64 + n * 16 + lm;
                Cout[(size_t)row * ldc + col] = acc[m][n][r];
            }
#undef TILEOP
#undef QUAD
#undef RD_A
#undef RD_B
#undef STAGE_A
#undef STAGE_B
}

// ---------------- Fused: RoPE in-place on Q,K  +  V transpose -> VT (B,H,D,S)
__global__ __launch_bounds__(256) void rope_vt(u16* __restrict__ qkv, u16* __restrict__ VT) {
    __shared__ u16 T[64 * 136];
    const int tid = threadIdx.x;
    const int s0 = blockIdx.x * 64;
    const int bh = blockIdx.y;
    const int b = bh >> 4, h = bh & 15;
#pragma unroll
    for (int p = 0; p < 4; p++) {
        int sl = p * 16 + (tid >> 4);
        int d0 = (tid & 15) * 8;
        *(us8*)&T[sl * 136 + d0] =
            *(const us8*)(qkv + ((size_t)(b * 2048 + s0 + sl)) * 6144 + 4096 + h * 128 + d0);
    }
#pragma unroll
    for (int p = 0; p < 2; p++) {
        int task = p * 256 + tid;
        int sl = task >> 3;
        int jg = task & 7;
        size_t base = ((size_t)(b * 2048 + s0 + sl)) * 6144 + h * 128 + jg * 8;
        us8 qlo = *(const us8*)(qkv + base);
        us8 qhi = *(const us8*)(qkv + base + 64);
        us8 klo = *(const us8*)(qkv + base + 2048);
        us8 khi = *(const us8*)(qkv + base + 2048 + 64);
        us8 oql, oqh, okl, okh;
        float s = (float)(s0 + sl);
#pragma unroll
        for (int e = 0; e < 8; e++) {
            int j = jg * 8 + e;
            float inv = __expf((float)j * (-9.210340371976184f / 64.f));
            float ang = s * inv;
            float sn, c;
            __sincosf(ang, &sn, &c);
            float q1 = b2f(qlo[e]), q2 = b2f(qhi[e]);
            oql[e] = f2b(q1 * c - q2 * sn);
            oqh[e] = f2b(q2 * c + q1 * sn);
            float k1 = b2f(klo[e]), k2 = b2f(khi[e]);
            okl[e] = f2b(k1 * c - k2 * sn);
            okh[e] = f2b(k2 * c + k1 * sn);
        }
        *(us8*)(qkv + base) = oql;
        *(us8*)(qkv + base + 64) = oqh;
        *(us8*)(qkv + base + 2048) = okl;
        *(us8*)(qkv + base + 2048 + 64) = okh;
    }
    __syncthreads();
#pragma unroll
    for (int p = 0; p < 4; p++) {
        int idx = p * 256 + tid;
        int d = idx & 127;
        int sg = idx >> 7;
        us8 v;
#pragma unroll
        for (int i = 0; i < 8; i++) v[i] = T[(sg * 8 + i) * 136 + d];
        *(us8*)&VT[((size_t)bh * 128 + d) * 2048 + s0 + sg * 8] = v;
    }
}

// ---------------- Flash attention v5: balanced causal pairing (33 qg-tile units/block).
#define ATT_SCALE 0.08838834764831845f

__global__ __launch_bounds__(256, 2) void attn_flash(const u16* __restrict__ qkv, const u16* __restrict__ VT,
                                                     u16* __restrict__ AO) {
    const int bid = blockIdx.x;
    const int swz = (bid & 7) * 64 + (bid >> 3);
    const int bh = swz >> 4;          // 0..31
    const int pair = swz & 15;        // 0..15
    const int b = bh >> 4, h = bh & 15;
    const int tid = threadIdx.x, lane = tid & 63, wave = tid >> 6;
    const int lm = lane & 15, lq = lane >> 4;

    const int jq0 = 31 - pair;        // high q-subtile (64-row units), always active
    const int jq1 = pair;             // low q-subtile, active for kt <= jq1
    const int ktmax = jq0;

    __shared__ u16 Kt[64 * 136];      // [kpos][d]
    __shared__ u16 Vt[128 * 72];      // [d][kpos]

    bf8_t qf[2][4];
#pragma unroll
    for (int qg = 0; qg < 2; qg++) {
        const int jqv = qg ? jq1 : jq0;
        const u16* Qrow = qkv + ((size_t)(b * 2048 + jqv * 64 + wave * 16 + lm)) * 6144 + h * 128;
#pragma unroll
        for (int ks = 0; ks < 4; ks++)
            qf[qg][ks] = *(const bf8_t*)(Qrow + ks * 32 + lq * 8);
    }

    f32x4 Of[2][8] = {};
    float mrun[2] = {-3.0e38f, -3.0e38f}, lrun[2] = {0.f, 0.f};

    const u16* Kbase = qkv + (size_t)b * 2048 * 6144 + 2048 + h * 128;
    const u16* VTbase = VT + (size_t)bh * 128 * 2048;

    const int krow = tid >> 4;        // 0..15
    const int kcol = (tid & 15) * 8;
    const int vrow = tid >> 3;        // 0..31
    const int vcol = (tid & 7) * 8;

    us8 kreg[4], vreg[4];
#pragma unroll
    for (int p = 0; p < 4; p++) {
        kreg[p] = *(const us8*)(Kbase + (size_t)(p * 16 + krow) * 6144 + kcol);
        vreg[p] = *(const us8*)(VTbase + (size_t)(p * 32 + vrow) * 2048 + vcol);
    }

    for (int kt = 0; kt <= ktmax; kt++) {
        __syncthreads();
#pragma unroll
        for (int p = 0; p < 4; p++) {
            *(us8*)&Kt[(p * 16 + krow) * 136 + kcol] = kreg[p];
            *(us8*)&Vt[(p * 32 + vrow) * 72 + vcol] = vreg[p];
        }
        __syncthreads();
        {   // prefetch next tile (clamped; final redundant reload discarded)
            int kn = (kt + 1 <= ktmax ? kt + 1 : ktmax) * 64;
#pragma unroll
            for (int p = 0; p < 4; p++) {
                kreg[p] = *(const us8*)(Kbase + (size_t)(kn + p * 16 + krow) * 6144 + kcol);
                vreg[p] = *(const us8*)(VTbase + (size_t)(p * 32 + vrow) * 2048 + kn + vcol);
            }
        }

        const bool act1 = (kt <= jq1);
        u64 pk[2][4];
#pragma unroll
        for (int qg = 0; qg < 2; qg++) {
            if (qg == 0 || act1) {
                const int jqv = qg ? jq1 : jq0;
                float sv[4][4];
#pragma unroll
                for (int nb = 0; nb < 4; nb++) {
                    f32x4 a = {};
#pragma unroll
                    for (int ks = 0; ks < 4; ks++) {
                        bf8_t kf = *(const bf8_t*)&Kt[(nb * 16 + lm) * 136 + ks * 32 + lq * 8];
                        a = mfma16(kf, qf[qg][ks], a);
                    }
#pragma unroll
                    for (int r = 0; r < 4; r++) sv[nb][r] = a[r] * ATT_SCALE;
                }
                if (kt == jqv) {
                    int qglob = jqv * 64 + wave * 16 + lm;
#pragma unroll
                    for (int nb = 0; nb < 4; nb++)
#pragma unroll
                        for (int r = 0; r < 4; r++)
                            if (kt * 64 + nb * 16 + lq * 4 + r > qglob) sv[nb][r] = -3.0e38f;
                }
                float mx = -3.0e38f;
#pragma unroll
                for (int nb = 0; nb < 4; nb++)
#pragma unroll
                    for (int r = 0; r < 4; r++) mx = fmaxf(mx, sv[nb][r]);
                mx = fmaxf(mx, __shfl_xor(mx, 16, 64));
                mx = fmaxf(mx, __shfl_xor(mx, 32, 64));
                float mnew = fmaxf(mrun[qg], mx);
                float a_ = __expf(mrun[qg] - mnew);
                float rs = 0.f;
#pragma unroll
                for (int nb = 0; nb < 4; nb++) {
                    float e0 = __expf(sv[nb][0] - mnew), e1 = __expf(sv[nb][1] - mnew);
                    float e2 = __expf(sv[nb][2] - mnew), e3 = __expf(sv[nb][3] - mnew);
                    rs += (e0 + e1) + (e2 + e3);
                    unsigned int lo = (unsigned int)f2b(e0) | ((unsigned int)f2b(e1) << 16);
                    unsigned int hi = (unsigned int)f2b(e2) | ((unsigned int)f2b(e3) << 16);
                    pk[qg][nb] = (u64)lo | ((u64)hi << 32);
                }
                rs += __shfl_xor(rs, 16, 64);
                rs += __shfl_xor(rs, 32, 64);
                lrun[qg] = lrun[qg] * a_ + rs;
                mrun[qg] = mnew;
#pragma unroll
                for (int db = 0; db < 8; db++)
#pragma unroll
                    for (int r = 0; r < 4; r++) Of[qg][db][r] *= a_;
            }
        }

        const int slo = ((lq & 1) * 2) * 16 + lm;
        const int shi = slo + 16;
        const bool sel = (lq >> 1) != 0;
#pragma unroll
        for (int kk = 0; kk < 2; kk++) {
            union { u64 v[2]; bf8_t f; } pf[2];
#pragma unroll
            for (int qg = 0; qg < 2; qg++) {
                if (qg == 0 || act1) {
                    u64 lo0 = __shfl(pk[qg][2 * kk + 0], slo, 64);
                    u64 lo1 = __shfl(pk[qg][2 * kk + 1], slo, 64);
                    u64 hi0 = __shfl(pk[qg][2 * kk + 0], shi, 64);
                    u64 hi1 = __shfl(pk[qg][2 * kk + 1], shi, 64);
                    pf[qg].v[0] = sel ? lo1 : lo0;
                    pf[qg].v[1] = sel ? hi1 : hi0;
                }
            }
#pragma unroll
            for (int db = 0; db < 8; db++) {
                bf8_t vf = *(const bf8_t*)&Vt[(db * 16 + lm) * 72 + kk * 32 + lq * 8];
                Of[0][db] = mfma16(vf, pf[0].f, Of[0][db]);
                if (act1) Of[1][db] = mfma16(vf, pf[1].f, Of[1][db]);
            }
        }
    }
#pragma unroll
    for (int qg = 0; qg < 2; qg++) {
        const int jqv = qg ? jq1 : jq0;
        float invl = 1.f / lrun[qg];
        size_t rowbase = (size_t)(b * 2048 + jqv * 64 + wave * 16 + lm) * 2048 + h * 128;
#pragma unroll
        for (int db = 0; db < 8; db++) {
            ushort4 o;
            o.x = f2b(Of[qg][db][0] * invl);
            o.y = f2b(Of[qg][db][1] * invl);
            o.z = f2b(Of[qg][db][2] * invl);
            o.w = f2b(Of[qg][db][3] * invl);
            *(ushort4*)(AO + rowbase + db * 16 + lq * 4) = o;
        }
    }
}

extern "C" void kernel_launch(void* const* d_in, const int* in_sizes, int n_in,
                              void* d_out, int out_size, void* d_ws, size_t ws_size,
                              hipStream_t stream) {
    const float* x     = (const float*)d_in[0];
    const float* w_qkv = (const float*)d_in[1];
    const float* w_o   = (const float*)d_in[2];
    float* out = (float*)d_out;
    u16* ws = (u16*)d_ws;

    u16* qkvb  = ws;                    // 25,165,824
    u16* VT    = ws + 25165824;         //  8,388,608
    u16* AO    = ws + 33554432;         //  8,388,608
    u16* xb    = ws + 41943040;         //  8,388,608
    u16* wqkvb = ws + 50331648;         // 12,582,912
    u16* wob   = ws + 62914560;         //  4,194,304

    f32_to_bf16<<<4096, 256, 0, stream>>>(x, xb, 1048576);
    f32_to_bf16<<<6144, 256, 0, stream>>>(w_qkv, wqkvb, 1572864);
    f32_to_bf16<<<2048, 256, 0, stream>>>(w_o, wob, 524288);
    gemm192<<<512, 512, 0, stream>>>(xb, wqkvb, qkvb, 6144);    // QKV: 16x32, 2 exact rounds
    rope_vt<<<dim3(32, 32), 256, 0, stream>>>(qkvb, VT);
    attn_flash<<<dim3(512), 256, 0, stream>>>(qkvb, VT, AO);
    gemm_op<<<256, 512, 0, stream>>>(AO, wob, out, 2048);       // out: 32x8, 1 exact round
}